// Round 6
// baseline (330.661 us; speedup 1.0000x reference)
//
#include <hip/hip_runtime.h>
#include <math.h>

#define DIM   16384
#define NOBS  8192
#define EPSN  1e-20f

__device__ __forceinline__ float softf(float v, float tau) {
    float a = fmaxf(fabsf(v) - tau, 0.0f);
    return copysignf(a, v);   // v==0 -> +0, matches sign(0)*x == 0
}

__device__ __forceinline__ float dot4(float4 a, float4 b) {
    return a.x * b.x + a.y * b.y + a.z * b.z + a.w * b.w;
}

__device__ __forceinline__ float sum16(const float* p) {
    const float4* q = (const float4*)p;
    float4 s0 = q[0], s1 = q[1], s2 = q[2], s3 = q[3];
    float a = (s0.x + s0.y) + (s0.z + s0.w);
    float b = (s1.x + s1.y) + (s1.z + s1.w);
    float c = (s2.x + s2.y) + (s2.z + s2.w);
    float d = (s3.x + s3.y) + (s3.z + s3.w);
    return (a + b) + (c + d);
}

// ---------------------------------------------------------------------------
// K1: fused  r = A@x_cur - b,  r_old = A@x_old - b,  grad_partial = A^T r
// 256 blocks x 1024 threads; block owns 32 rows; thread owns 16 columns.
// Depth-2 register prefetch (B0/B1 ping-pong) + raw barrier with lgkmcnt-only
// wait: next-row loads stay in flight ACROSS the barrier.
//
// amdgpu_waves_per_eu(4,4): R4/R5 post-mortem — the allocator's default
// heuristic targets 8 waves/EU (64-VGPR budget) and spilled the ~80-reg
// pipeline state to scratch (+0.5 GB HBM, 330 us). launch_bounds' 2nd arg is
// only a MINIMUM-occupancy floor, so it didn't move the budget. Pinning
// waves/EU to exactly 4 raises the cap to 128 VGPRs (1 block/CU) and removes
// the incentive to spill.
// ---------------------------------------------------------------------------
__global__ __launch_bounds__(1024)
__attribute__((amdgpu_waves_per_eu(4, 4)))
void k1_fused(
    const float* __restrict__ A, const float* __restrict__ xc,
    const float* __restrict__ xo, const float* __restrict__ b,
    float* __restrict__ ws_gp,   // [256][DIM] grad partials
    float* __restrict__ ws_sc)   // [256][2]   (sum r^2, sum r_old^2)
{
    const int t   = threadIdx.x;
    const int bid = blockIdx.x;
    __shared__ __align__(16) float redc[2][16];
    __shared__ __align__(16) float redo[2][16];
    __shared__ float bsh[32];

    const int row0 = bid * 32;
    if (t < 32) bsh[t] = b[row0 + t];

    const float4* xc4 = (const float4*)xc;
    const float4* xo4 = (const float4*)xo;

    float4 xcq[4], xoq[4], gpq[4];
#pragma unroll
    for (int k = 0; k < 4; ++k) {
        xcq[k] = xc4[k * 1024 + t];
        xoq[k] = xo4[k * 1024 + t];
        gpq[k] = make_float4(0.f, 0.f, 0.f, 0.f);
    }
    __syncthreads();   // bsh visible (one-time full drain, harmless)

    const float4* Abase = (const float4*)A + (size_t)row0 * (DIM / 4);
    float4 b0q[4], b1q[4];
#pragma unroll
    for (int k = 0; k < 4; ++k) b0q[k] = Abase[k * 1024 + t];
#pragma unroll
    for (int k = 0; k < 4; ++k) b1q[k] = Abase[(DIM / 4) + k * 1024 + t];

    float sum_r2 = 0.f, sum_ro2 = 0.f;

#define K1_BODY(ROW, BQ, PAR)                                                  \
    do {                                                                       \
        float dc = 0.f, dn = 0.f;                                              \
        _Pragma("unroll")                                                      \
        for (int k = 0; k < 4; ++k) {                                          \
            dc += dot4(BQ[k], xcq[k]);                                         \
            dn += dot4(BQ[k], xoq[k]);                                         \
        }                                                                      \
        _Pragma("unroll")                                                      \
        for (int off = 32; off > 0; off >>= 1) {                               \
            dc += __shfl_down(dc, off);                                        \
            dn += __shfl_down(dn, off);                                        \
        }                                                                      \
        if ((t & 63) == 0) {                                                   \
            redc[PAR][t >> 6] = dc;                                            \
            redo[PAR][t >> 6] = dn;                                            \
        }                                                                      \
        asm volatile("s_waitcnt lgkmcnt(0)" ::: "memory");                     \
        __builtin_amdgcn_s_barrier();                                          \
        asm volatile("" ::: "memory");                                         \
        float rc = sum16(redc[PAR]) - bsh[ROW];                                \
        if (t == 0) sum_r2 += rc * rc;                                         \
        if (t == 1) {                                                          \
            float ro = sum16(redo[PAR]) - bsh[ROW];                            \
            sum_ro2 += ro * ro;                                                \
        }                                                                      \
        _Pragma("unroll")                                                      \
        for (int k = 0; k < 4; ++k) {                                          \
            gpq[k].x += BQ[k].x * rc;                                          \
            gpq[k].y += BQ[k].y * rc;                                          \
            gpq[k].z += BQ[k].z * rc;                                          \
            gpq[k].w += BQ[k].w * rc;                                          \
        }                                                                      \
        if ((ROW) + 2 < 32) {                                                  \
            const float4* An = Abase + (size_t)((ROW) + 2) * (DIM / 4);        \
            _Pragma("unroll")                                                  \
            for (int k = 0; k < 4; ++k) BQ[k] = An[k * 1024 + t];              \
        }                                                                      \
    } while (0)

    for (int rr = 0; rr < 32; rr += 2) {
        K1_BODY(rr,     b0q, 0);
        K1_BODY(rr + 1, b1q, 1);
    }
#undef K1_BODY

    float4* gp4 = (float4*)(ws_gp + (size_t)bid * DIM);
#pragma unroll
    for (int k = 0; k < 4; ++k) gp4[k * 1024 + t] = gpq[k];
    if (t == 0) ws_sc[bid * 2 + 0] = sum_r2;
    if (t == 1) ws_sc[bid * 2 + 1] = sum_ro2;
}

// ---------------------------------------------------------------------------
// K2: fused partial-sum + finalize grad + all per-column stats.
// 64 blocks x 1024 threads. Block owns 256 columns; thread (s = t>>8, c = t&255)
// sums partials [64s, 64s+64) for column c; cross-slice combine in LDS; then
// threads t<256 compute the 10 stats (deterministic order == previous rounds).
// ---------------------------------------------------------------------------
__global__ __launch_bounds__(1024) void k2_fused(
    const float* __restrict__ ws_gp, const float* __restrict__ xc,
    const float* __restrict__ xo, const float* __restrict__ mu,
    const float* __restrict__ sm,
    float* __restrict__ grad, float* __restrict__ ws_red)  // [64][10]
{
    const int t = threadIdx.x;
    const int s = t >> 8;
    const int c = t & 255;
    const int j = blockIdx.x * 256 + c;

    __shared__ float sums[4][256];
    __shared__ float sred[4][10];

    const float* base = ws_gp + (size_t)(s * 64) * DIM + j;
    float a0 = 0.f, a1 = 0.f, a2 = 0.f, a3 = 0.f;
#pragma unroll
    for (int i = 0; i < 16; ++i) {
        a0 += base[(size_t)(4 * i + 0) * DIM];
        a1 += base[(size_t)(4 * i + 1) * DIM];
        a2 += base[(size_t)(4 * i + 2) * DIM];
        a3 += base[(size_t)(4 * i + 3) * DIM];
    }
    sums[s][c] = (a0 + a1) + (a2 + a3);
    __syncthreads();

    if (t < 256) {
        const int jj = blockIdx.x * 256 + t;
        float g = (sums[0][t] + sums[1][t]) + (sums[2][t] + sums[3][t]);
        grad[jj] = g;

        const float x  = xc[jj];
        const float xv = xo[jj];
        const float z  = (x == 0.f) ? 1.f : 0.f;
        const float nz = 1.f - z;
        const float d  = x - xv;
        const float m = mu[0], L = sm[0];
        const float invL = 1.f / L;
        const float pv = softf(x - g * invL, m * invL);
        const float sv = x - pv;

        float vals[10];
        vals[0] = g * g * z;
        vals[1] = g * g * nz;
        vals[2] = d * d * z;
        vals[3] = d * d * nz;
        vals[4] = g * d * z;
        vals[5] = g * d * nz;
        vals[6] = fabsf(x);
        vals[7] = fabsf(xv);
        vals[8] = sv * sv * z;
        vals[9] = sv * sv * nz;

#pragma unroll
        for (int k = 0; k < 10; ++k) {
#pragma unroll
            for (int off = 32; off > 0; off >>= 1)
                vals[k] += __shfl_down(vals[k], off);
        }
        if ((t & 63) == 0) {
#pragma unroll
            for (int k = 0; k < 10; ++k) sred[t >> 6][k] = vals[k];
        }
    }
    __syncthreads();
    if (t < 10)
        ws_red[blockIdx.x * 10 + t] =
            (sred[0][t] + sred[1][t]) + (sred[2][t] + sred[3][t]);
}

// ---------------------------------------------------------------------------
// K34: fused scalar finish (redundant per block) + per-column update.
// 64 blocks x 256 threads. Phase A: batched reduce of 12 scalars + feats +
// step MLP -> alpha in LDS. Phase B: channels -> conv MLP -> soft-threshold.
// ---------------------------------------------------------------------------
__global__ __launch_bounds__(256) void k34_update(
    const float* __restrict__ ws_sc,   // [256][2]
    const float* __restrict__ ws_red,  // [64][10]
    const float* __restrict__ grad, const float* __restrict__ xc,
    const float* __restrict__ xo, const float* __restrict__ mu,
    const float* __restrict__ sm,
    const float* __restrict__ Ws1, const float* __restrict__ Ws2,
    const float* __restrict__ Ws3, const float* __restrict__ Ws4,
    const float* __restrict__ Wu1, const float* __restrict__ Wu2,
    const float* __restrict__ Wu3, const float* __restrict__ Wu4,
    float* __restrict__ out)
{
    __shared__ float w1[160], w2[400], w3[400], w4[40];
    __shared__ float sred[4][12];
    __shared__ float feats[12];
    __shared__ float ba[32], bb[32];
    __shared__ float alpha_sh[12];   // alpha[8], grad_norm, diff_norm, stop_norm

    const int t = threadIdx.x;
    for (int i = t; i < 160; i += 256) w1[i] = Wu1[i];
    for (int i = t; i < 400; i += 256) w2[i] = Wu2[i];
    for (int i = t; i < 400; i += 256) w3[i] = Wu3[i];
    if (t < 40) w4[t] = Wu4[t];

    // batched scalar reduction: 12 values, one barrier
    float v[12];
    v[0] = ws_sc[2 * t + 0];
    v[1] = ws_sc[2 * t + 1];
#pragma unroll
    for (int k = 0; k < 10; ++k) v[2 + k] = (t < 64) ? ws_red[t * 10 + k] : 0.f;
#pragma unroll
    for (int k = 0; k < 12; ++k) {
#pragma unroll
        for (int off = 32; off > 0; off >>= 1) v[k] += __shfl_down(v[k], off);
    }
    if ((t & 63) == 0) {
#pragma unroll
        for (int k = 0; k < 12; ++k) sred[t >> 6][k] = v[k];
    }
    __syncthreads();

    if (t == 0) {
        float r[12];
#pragma unroll
        for (int k = 0; k < 12; ++k)
            r[k] = (sred[0][k] + sred[1][k]) + (sred[2][k] + sred[3][k]);
        const float sum_r2 = r[0], sum_ro2 = r[1];
        const float gz2 = r[2], gnz2 = r[3], dz2 = r[4], dnz2 = r[5];
        const float gdz = r[6], gdnz = r[7], sxc = r[8], sxo = r[9];
        const float svz2 = r[10], svnz2 = r[11];

        const float grad_norm = sqrtf(gz2 + gnz2);
        const float diff_norm = sqrtf(dz2 + dnz2);
        const float stop_norm = sqrtf(svz2 + svnz2);
        const float m = mu[0];
        float smooth = 0.5f * sum_r2, old_smooth = 0.5f * sum_ro2;
        float nonsm = m * sxc, old_nonsm = m * sxo;
        float loss = smooth + nonsm, old_loss = old_smooth + old_nonsm;

        float fg = (grad_norm > EPSN) ? 1.f / grad_norm : 1.f;
        float fd = (diff_norm > EPSN) ? 1.f / diff_norm : 1.f;
        float fs = (stop_norm > EPSN) ? 1.f / stop_norm : 1.f;

        feats[0]  = m;
        feats[1]  = log1pf(old_loss) - log1pf(loss);
        feats[2]  = log1pf(old_smooth) - log1pf(smooth);
        feats[3]  = log1pf(old_nonsm) - log1pf(nonsm);
        feats[4]  = log1pf(grad_norm * fg * sqrtf(gz2));
        feats[5]  = log1pf(grad_norm * fg * sqrtf(gnz2));
        feats[6]  = log1pf(diff_norm * fd * sqrtf(dz2));
        feats[7]  = log1pf(diff_norm * fd * sqrtf(dnz2));
        feats[8]  = log1pf(stop_norm * fs * sqrtf(svz2));
        feats[9]  = log1pf(stop_norm * fs * sqrtf(svnz2));
        feats[10] = gdz  * fg * fd;
        feats[11] = gdnz * fg * fd;
        alpha_sh[8]  = grad_norm;
        alpha_sh[9]  = diff_norm;
        alpha_sh[10] = stop_norm;
    }
    __syncthreads();

    // step MLP: 12 -> 30 -> 20 -> 10 -> 8
    if (t < 30) {
        float s0 = 0.f;
#pragma unroll
        for (int k = 0; k < 12; ++k) s0 += Ws1[t * 12 + k] * feats[k];
        ba[t] = fmaxf(s0, 0.f);
    }
    __syncthreads();
    if (t < 20) {
        float s0 = 0.f;
#pragma unroll
        for (int k = 0; k < 30; ++k) s0 += Ws2[t * 30 + k] * ba[k];
        bb[t] = fmaxf(s0, 0.f);
    }
    __syncthreads();
    if (t < 10) {
        float s0 = 0.f;
#pragma unroll
        for (int k = 0; k < 20; ++k) s0 += Ws3[t * 20 + k] * bb[k];
        ba[t] = fmaxf(s0, 0.f);
    }
    __syncthreads();
    if (t < 8) {
        float s0 = 0.f;
#pragma unroll
        for (int k = 0; k < 10; ++k) s0 += Ws4[t * 10 + k] * ba[k];
        alpha_sh[t] = s0;
    }
    __syncthreads();

    // ---- phase B: per-column update ----
    const int j = blockIdx.x * 256 + t;
    const float m = mu[0], L = sm[0];
    const float invL = 1.f / L;
    const float gn = alpha_sh[8], dn = alpha_sh[9], sn = alpha_sh[10];
    float a[8];
#pragma unroll
    for (int k = 0; k < 8; ++k) a[k] = alpha_sh[k];

    const float g  = grad[j];
    const float x  = xc[j];
    const float xv = xo[j];
    const float z  = (x == 0.f) ? 1.f : 0.f;
    const float nz = 1.f - z;

    const float fg = (gn > EPSN) ? 1.f / gn : 1.f;
    const float fd = (dn > EPSN) ? 1.f / dn : 1.f;
    const float fs = (sn > EPSN) ? 1.f / sn : 1.f;
    const float gg = (gn > EPSN) ? g : gn * g;   // grad_norm * normalized_grad

    const float pv = softf(x - gg * invL, m * invL);
    const float sv = x - pv;

    const float gN = g * fg;
    const float dN = (x - xv) * fd;
    const float sN = sv * fs;

    float ch[8];
    ch[0] = a[0] * gN * z;
    ch[1] = a[1] * gN * nz;
    ch[2] = a[2] * sN * z;
    ch[3] = a[3] * sN * nz;
    ch[4] = a[4] * dN * z;
    ch[5] = a[5] * dN * nz;
    ch[6] = a[6] * (gN * nz) * (dN * nz);
    ch[7] = a[7] * (gN * z) * (dN * z);

    float h1[20];
#pragma unroll
    for (int i = 0; i < 20; ++i) {
        float s0 = 0.f;
#pragma unroll
        for (int k = 0; k < 8; ++k) s0 += w1[i * 8 + k] * ch[k];
        h1[i] = fmaxf(s0, 0.f);
    }
    float h2[20];
#pragma unroll
    for (int i = 0; i < 20; ++i) {
        float s0 = 0.f;
#pragma unroll
        for (int k = 0; k < 20; ++k) s0 += w2[i * 20 + k] * h1[k];
        h2[i] = fmaxf(s0, 0.f);
    }
    float h3[20];
#pragma unroll
    for (int i = 0; i < 20; ++i) {
        float s0 = 0.f;
#pragma unroll
        for (int k = 0; k < 20; ++k) s0 += w3[i * 20 + k] * h2[k];
        h3[i] = fmaxf(s0, 0.f);
    }
    float d0 = 0.f, d1 = 0.f;
#pragma unroll
    for (int k = 0; k < 20; ++k) {
        d0 += w4[k] * h3[k];
        d1 += w4[20 + k] * h3[k];
    }

    const float dir1 = d0 * z;
    const float dir2 = d1 * nz;
    const float arg  = x + (dir1 - gg + dn * dir2) * invL;
    out[j] = softf(arg, m * invL);
}

// ---------------------------------------------------------------------------
extern "C" void kernel_launch(void* const* d_in, const int* in_sizes, int n_in,
                              void* d_out, int out_size, void* d_ws, size_t ws_size,
                              hipStream_t stream)
{
    const float* x_old = (const float*)d_in[0];
    const float* x_cur = (const float*)d_in[1];
    const float* A     = (const float*)d_in[2];
    const float* b     = (const float*)d_in[3];
    const float* mu    = (const float*)d_in[4];
    const float* sm    = (const float*)d_in[5];
    const float* Wu1   = (const float*)d_in[6];
    const float* Wu2   = (const float*)d_in[7];
    const float* Wu3   = (const float*)d_in[8];
    const float* Wu4   = (const float*)d_in[9];
    const float* Ws1   = (const float*)d_in[10];
    const float* Ws2   = (const float*)d_in[11];
    const float* Ws3   = (const float*)d_in[12];
    const float* Ws4   = (const float*)d_in[13];
    float* out = (float*)d_out;

    float* ws      = (float*)d_ws;
    float* ws_gp   = ws;                           // 256 * DIM
    float* ws_sc   = ws_gp  + (size_t)256 * DIM;   // 512
    float* ws_red  = ws_sc  + 512;                 // 640
    float* ws_grad = ws_red + 640;                 // DIM

    k1_fused  <<<256, 1024, 0, stream>>>(A, x_cur, x_old, b, ws_gp, ws_sc);
    k2_fused  <<<64,  1024, 0, stream>>>(ws_gp, x_cur, x_old, mu, sm, ws_grad, ws_red);
    k34_update<<<64,  256,  0, stream>>>(ws_sc, ws_red, ws_grad, x_cur, x_old, mu, sm,
                                         Ws1, Ws2, Ws3, Ws4, Wu1, Wu2, Wu3, Wu4, out);
}

// Round 7
// 158.797 us; speedup vs baseline: 2.0823x; 2.0823x over previous
//
#include <hip/hip_runtime.h>
#include <math.h>

#define DIM   16384
#define NOBS  8192
#define EPSN  1e-20f

__device__ __forceinline__ float softf(float v, float tau) {
    float a = fmaxf(fabsf(v) - tau, 0.0f);
    return copysignf(a, v);   // v==0 -> +0, matches sign(0)*x == 0
}

__device__ __forceinline__ float dot4(float4 a, float4 b) {
    return a.x * b.x + a.y * b.y + a.z * b.z + a.w * b.w;
}

__device__ __forceinline__ float sum16(const float* p) {
    const float4* q = (const float4*)p;
    float4 s0 = q[0], s1 = q[1], s2 = q[2], s3 = q[3];
    float a = (s0.x + s0.y) + (s0.z + s0.w);
    float b = (s1.x + s1.y) + (s1.z + s1.w);
    float c = (s2.x + s2.y) + (s2.z + s2.w);
    float d = (s3.x + s3.y) + (s3.z + s3.w);
    return (a + b) + (c + d);
}

// ---------------------------------------------------------------------------
// K1: fused  r = A@x_cur - b,  r_old = A@x_old - b,  grad_partial = A^T r
// 256 blocks x 1024 threads; block owns 32 rows; thread owns 16 columns.
//
// R6 post-mortem: VGPR stuck at 64 (8-wave/EU heuristic), ~80-reg array state
// spilled to scratch every row (+650 MB HBM). Fix:
//  - xc/xo live in LDS (128 KB), not registers: cuts 32 VGPRs AND decouples
//    x-reads (lgkmcnt) from the A-prefetch (vmcnt) — issue-ordered vmcnt
//    would otherwise force the prefetch to drain at each use of x.
//  - 131 KB LDS forces 1 block/CU = 4 waves/EU, so the backend's occupancy
//    calculation itself raises the VGPR budget to 128 (no attribute games).
//  - A rows: depth-2 register ping-pong (b0q/b1q) + raw barrier with
//    lgkmcnt-only wait -> prefetch stays in flight across the barrier.
// ---------------------------------------------------------------------------
__global__ __launch_bounds__(1024) void k1_fused(
    const float* __restrict__ A, const float* __restrict__ xc,
    const float* __restrict__ xo, const float* __restrict__ b,
    float* __restrict__ ws_gp,   // [256][DIM] grad partials
    float* __restrict__ ws_sc)   // [256][2]   (sum r^2, sum r_old^2)
{
    const int t   = threadIdx.x;
    const int bid = blockIdx.x;

    __shared__ __align__(16) float xcs[DIM];     // 64 KB
    __shared__ __align__(16) float xos[DIM];     // 64 KB
    __shared__ __align__(16) float redc[2][16];
    __shared__ __align__(16) float redo[2][16];
    __shared__ float bsh[32];

    const int row0 = bid * 32;
    if (t < 32) bsh[t] = b[row0 + t];

    // stage xc/xo into LDS (one-time 128 KB per block)
    {
        const float4* xc4g = (const float4*)xc;
        const float4* xo4g = (const float4*)xo;
        float4* xcs4 = (float4*)xcs;
        float4* xos4 = (float4*)xos;
#pragma unroll
        for (int k = 0; k < 4; ++k) {
            xcs4[k * 1024 + t] = xc4g[k * 1024 + t];
            xos4[k * 1024 + t] = xo4g[k * 1024 + t];
        }
    }

    float4 gpq[4];
#pragma unroll
    for (int k = 0; k < 4; ++k) gpq[k] = make_float4(0.f, 0.f, 0.f, 0.f);

    const float4* Abase = (const float4*)A + (size_t)row0 * (DIM / 4);
    float4 b0q[4], b1q[4];
#pragma unroll
    for (int k = 0; k < 4; ++k) b0q[k] = Abase[k * 1024 + t];
#pragma unroll
    for (int k = 0; k < 4; ++k) b1q[k] = Abase[(DIM / 4) + k * 1024 + t];

    __syncthreads();   // xcs/xos + bsh visible (one-time full drain)

    const float4* xcs4 = (const float4*)xcs;
    const float4* xos4 = (const float4*)xos;
    float sum_r2 = 0.f, sum_ro2 = 0.f;

#define K1_BODY(ROW, BQ, PAR)                                                  \
    do {                                                                       \
        float dc = 0.f, dn = 0.f;                                              \
        _Pragma("unroll")                                                      \
        for (int k = 0; k < 4; ++k) {                                          \
            float4 xct = xcs4[k * 1024 + t];   /* LDS: lgkm, not vmcnt */      \
            float4 xot = xos4[k * 1024 + t];                                   \
            dc += dot4(BQ[k], xct);                                            \
            dn += dot4(BQ[k], xot);                                            \
        }                                                                      \
        _Pragma("unroll")                                                      \
        for (int off = 32; off > 0; off >>= 1) {                               \
            dc += __shfl_down(dc, off);                                        \
            dn += __shfl_down(dn, off);                                        \
        }                                                                      \
        if ((t & 63) == 0) {                                                   \
            redc[PAR][t >> 6] = dc;                                            \
            redo[PAR][t >> 6] = dn;                                            \
        }                                                                      \
        asm volatile("s_waitcnt lgkmcnt(0)" ::: "memory");                     \
        __builtin_amdgcn_s_barrier();                                          \
        asm volatile("" ::: "memory");                                         \
        float rc = sum16(redc[PAR]) - bsh[ROW];                                \
        if (t == 0) sum_r2 += rc * rc;                                         \
        if (t == 1) {                                                          \
            float ro = sum16(redo[PAR]) - bsh[ROW];                            \
            sum_ro2 += ro * ro;                                                \
        }                                                                      \
        _Pragma("unroll")                                                      \
        for (int k = 0; k < 4; ++k) {                                          \
            gpq[k].x += BQ[k].x * rc;                                          \
            gpq[k].y += BQ[k].y * rc;                                          \
            gpq[k].z += BQ[k].z * rc;                                          \
            gpq[k].w += BQ[k].w * rc;                                          \
        }                                                                      \
        if ((ROW) + 2 < 32) {                                                  \
            const float4* An = Abase + (size_t)((ROW) + 2) * (DIM / 4);        \
            _Pragma("unroll")                                                  \
            for (int k = 0; k < 4; ++k) BQ[k] = An[k * 1024 + t];              \
        }                                                                      \
    } while (0)

    for (int rr = 0; rr < 32; rr += 2) {
        K1_BODY(rr,     b0q, 0);
        K1_BODY(rr + 1, b1q, 1);
    }
#undef K1_BODY

    float4* gp4 = (float4*)(ws_gp + (size_t)bid * DIM);
#pragma unroll
    for (int k = 0; k < 4; ++k) gp4[k * 1024 + t] = gpq[k];
    if (t == 0) ws_sc[bid * 2 + 0] = sum_r2;
    if (t == 1) ws_sc[bid * 2 + 1] = sum_ro2;
}

// ---------------------------------------------------------------------------
// K2: fused partial-sum + finalize grad + all per-column stats.
// 64 blocks x 1024 threads. Block owns 256 columns; thread (s = t>>8, c = t&255)
// sums partials [64s, 64s+64) for column c; cross-slice combine in LDS; then
// threads t<256 compute the 10 stats (deterministic order == previous rounds).
// ---------------------------------------------------------------------------
__global__ __launch_bounds__(1024) void k2_fused(
    const float* __restrict__ ws_gp, const float* __restrict__ xc,
    const float* __restrict__ xo, const float* __restrict__ mu,
    const float* __restrict__ sm,
    float* __restrict__ grad, float* __restrict__ ws_red)  // [64][10]
{
    const int t = threadIdx.x;
    const int s = t >> 8;
    const int c = t & 255;
    const int j = blockIdx.x * 256 + c;

    __shared__ float sums[4][256];
    __shared__ float sred[4][10];

    const float* base = ws_gp + (size_t)(s * 64) * DIM + j;
    float a0 = 0.f, a1 = 0.f, a2 = 0.f, a3 = 0.f;
#pragma unroll
    for (int i = 0; i < 16; ++i) {
        a0 += base[(size_t)(4 * i + 0) * DIM];
        a1 += base[(size_t)(4 * i + 1) * DIM];
        a2 += base[(size_t)(4 * i + 2) * DIM];
        a3 += base[(size_t)(4 * i + 3) * DIM];
    }
    sums[s][c] = (a0 + a1) + (a2 + a3);
    __syncthreads();

    if (t < 256) {
        const int jj = blockIdx.x * 256 + t;
        float g = (sums[0][t] + sums[1][t]) + (sums[2][t] + sums[3][t]);
        grad[jj] = g;

        const float x  = xc[jj];
        const float xv = xo[jj];
        const float z  = (x == 0.f) ? 1.f : 0.f;
        const float nz = 1.f - z;
        const float d  = x - xv;
        const float m = mu[0], L = sm[0];
        const float invL = 1.f / L;
        const float pv = softf(x - g * invL, m * invL);
        const float sv = x - pv;

        float vals[10];
        vals[0] = g * g * z;
        vals[1] = g * g * nz;
        vals[2] = d * d * z;
        vals[3] = d * d * nz;
        vals[4] = g * d * z;
        vals[5] = g * d * nz;
        vals[6] = fabsf(x);
        vals[7] = fabsf(xv);
        vals[8] = sv * sv * z;
        vals[9] = sv * sv * nz;

#pragma unroll
        for (int k = 0; k < 10; ++k) {
#pragma unroll
            for (int off = 32; off > 0; off >>= 1)
                vals[k] += __shfl_down(vals[k], off);
        }
        if ((t & 63) == 0) {
#pragma unroll
            for (int k = 0; k < 10; ++k) sred[t >> 6][k] = vals[k];
        }
    }
    __syncthreads();
    if (t < 10)
        ws_red[blockIdx.x * 10 + t] =
            (sred[0][t] + sred[1][t]) + (sred[2][t] + sred[3][t]);
}

// ---------------------------------------------------------------------------
// K34: fused scalar finish (redundant per block) + per-column update.
// 64 blocks x 256 threads. Phase A: batched reduce of 12 scalars + feats +
// step MLP -> alpha in LDS. Phase B: channels -> conv MLP -> soft-threshold.
// ---------------------------------------------------------------------------
__global__ __launch_bounds__(256) void k34_update(
    const float* __restrict__ ws_sc,   // [256][2]
    const float* __restrict__ ws_red,  // [64][10]
    const float* __restrict__ grad, const float* __restrict__ xc,
    const float* __restrict__ xo, const float* __restrict__ mu,
    const float* __restrict__ sm,
    const float* __restrict__ Ws1, const float* __restrict__ Ws2,
    const float* __restrict__ Ws3, const float* __restrict__ Ws4,
    const float* __restrict__ Wu1, const float* __restrict__ Wu2,
    const float* __restrict__ Wu3, const float* __restrict__ Wu4,
    float* __restrict__ out)
{
    __shared__ float w1[160], w2[400], w3[400], w4[40];
    __shared__ float sred[4][12];
    __shared__ float feats[12];
    __shared__ float ba[32], bb[32];
    __shared__ float alpha_sh[12];   // alpha[8], grad_norm, diff_norm, stop_norm

    const int t = threadIdx.x;
    for (int i = t; i < 160; i += 256) w1[i] = Wu1[i];
    for (int i = t; i < 400; i += 256) w2[i] = Wu2[i];
    for (int i = t; i < 400; i += 256) w3[i] = Wu3[i];
    if (t < 40) w4[t] = Wu4[t];

    // batched scalar reduction: 12 values, one barrier
    float v[12];
    v[0] = ws_sc[2 * t + 0];
    v[1] = ws_sc[2 * t + 1];
#pragma unroll
    for (int k = 0; k < 10; ++k) v[2 + k] = (t < 64) ? ws_red[t * 10 + k] : 0.f;
#pragma unroll
    for (int k = 0; k < 12; ++k) {
#pragma unroll
        for (int off = 32; off > 0; off >>= 1) v[k] += __shfl_down(v[k], off);
    }
    if ((t & 63) == 0) {
#pragma unroll
        for (int k = 0; k < 12; ++k) sred[t >> 6][k] = v[k];
    }
    __syncthreads();

    if (t == 0) {
        float r[12];
#pragma unroll
        for (int k = 0; k < 12; ++k)
            r[k] = (sred[0][k] + sred[1][k]) + (sred[2][k] + sred[3][k]);
        const float sum_r2 = r[0], sum_ro2 = r[1];
        const float gz2 = r[2], gnz2 = r[3], dz2 = r[4], dnz2 = r[5];
        const float gdz = r[6], gdnz = r[7], sxc = r[8], sxo = r[9];
        const float svz2 = r[10], svnz2 = r[11];

        const float grad_norm = sqrtf(gz2 + gnz2);
        const float diff_norm = sqrtf(dz2 + dnz2);
        const float stop_norm = sqrtf(svz2 + svnz2);
        const float m = mu[0];
        float smooth = 0.5f * sum_r2, old_smooth = 0.5f * sum_ro2;
        float nonsm = m * sxc, old_nonsm = m * sxo;
        float loss = smooth + nonsm, old_loss = old_smooth + old_nonsm;

        float fg = (grad_norm > EPSN) ? 1.f / grad_norm : 1.f;
        float fd = (diff_norm > EPSN) ? 1.f / diff_norm : 1.f;
        float fs = (stop_norm > EPSN) ? 1.f / stop_norm : 1.f;

        feats[0]  = m;
        feats[1]  = log1pf(old_loss) - log1pf(loss);
        feats[2]  = log1pf(old_smooth) - log1pf(smooth);
        feats[3]  = log1pf(old_nonsm) - log1pf(nonsm);
        feats[4]  = log1pf(grad_norm * fg * sqrtf(gz2));
        feats[5]  = log1pf(grad_norm * fg * sqrtf(gnz2));
        feats[6]  = log1pf(diff_norm * fd * sqrtf(dz2));
        feats[7]  = log1pf(diff_norm * fd * sqrtf(dnz2));
        feats[8]  = log1pf(stop_norm * fs * sqrtf(svz2));
        feats[9]  = log1pf(stop_norm * fs * sqrtf(svnz2));
        feats[10] = gdz  * fg * fd;
        feats[11] = gdnz * fg * fd;
        alpha_sh[8]  = grad_norm;
        alpha_sh[9]  = diff_norm;
        alpha_sh[10] = stop_norm;
    }
    __syncthreads();

    // step MLP: 12 -> 30 -> 20 -> 10 -> 8
    if (t < 30) {
        float s0 = 0.f;
#pragma unroll
        for (int k = 0; k < 12; ++k) s0 += Ws1[t * 12 + k] * feats[k];
        ba[t] = fmaxf(s0, 0.f);
    }
    __syncthreads();
    if (t < 20) {
        float s0 = 0.f;
#pragma unroll
        for (int k = 0; k < 30; ++k) s0 += Ws2[t * 30 + k] * ba[k];
        bb[t] = fmaxf(s0, 0.f);
    }
    __syncthreads();
    if (t < 10) {
        float s0 = 0.f;
#pragma unroll
        for (int k = 0; k < 20; ++k) s0 += Ws3[t * 20 + k] * bb[k];
        ba[t] = fmaxf(s0, 0.f);
    }
    __syncthreads();
    if (t < 8) {
        float s0 = 0.f;
#pragma unroll
        for (int k = 0; k < 10; ++k) s0 += Ws4[t * 10 + k] * ba[k];
        alpha_sh[t] = s0;
    }
    __syncthreads();

    // ---- phase B: per-column update ----
    const int j = blockIdx.x * 256 + t;
    const float m = mu[0], L = sm[0];
    const float invL = 1.f / L;
    const float gn = alpha_sh[8], dn = alpha_sh[9], sn = alpha_sh[10];
    float a[8];
#pragma unroll
    for (int k = 0; k < 8; ++k) a[k] = alpha_sh[k];

    const float g  = grad[j];
    const float x  = xc[j];
    const float xv = xo[j];
    const float z  = (x == 0.f) ? 1.f : 0.f;
    const float nz = 1.f - z;

    const float fg = (gn > EPSN) ? 1.f / gn : 1.f;
    const float fd = (dn > EPSN) ? 1.f / dn : 1.f;
    const float fs = (sn > EPSN) ? 1.f / sn : 1.f;
    const float gg = (gn > EPSN) ? g : gn * g;   // grad_norm * normalized_grad

    const float pv = softf(x - gg * invL, m * invL);
    const float sv = x - pv;

    const float gN = g * fg;
    const float dN = (x - xv) * fd;
    const float sN = sv * fs;

    float ch[8];
    ch[0] = a[0] * gN * z;
    ch[1] = a[1] * gN * nz;
    ch[2] = a[2] * sN * z;
    ch[3] = a[3] * sN * nz;
    ch[4] = a[4] * dN * z;
    ch[5] = a[5] * dN * nz;
    ch[6] = a[6] * (gN * nz) * (dN * nz);
    ch[7] = a[7] * (gN * z) * (dN * z);

    float h1[20];
#pragma unroll
    for (int i = 0; i < 20; ++i) {
        float s0 = 0.f;
#pragma unroll
        for (int k = 0; k < 8; ++k) s0 += w1[i * 8 + k] * ch[k];
        h1[i] = fmaxf(s0, 0.f);
    }
    float h2[20];
#pragma unroll
    for (int i = 0; i < 20; ++i) {
        float s0 = 0.f;
#pragma unroll
        for (int k = 0; k < 20; ++k) s0 += w2[i * 20 + k] * h1[k];
        h2[i] = fmaxf(s0, 0.f);
    }
    float h3[20];
#pragma unroll
    for (int i = 0; i < 20; ++i) {
        float s0 = 0.f;
#pragma unroll
        for (int k = 0; k < 20; ++k) s0 += w3[i * 20 + k] * h2[k];
        h3[i] = fmaxf(s0, 0.f);
    }
    float d0 = 0.f, d1 = 0.f;
#pragma unroll
    for (int k = 0; k < 20; ++k) {
        d0 += w4[k] * h3[k];
        d1 += w4[20 + k] * h3[k];
    }

    const float dir1 = d0 * z;
    const float dir2 = d1 * nz;
    const float arg  = x + (dir1 - gg + dn * dir2) * invL;
    out[j] = softf(arg, m * invL);
}

// ---------------------------------------------------------------------------
extern "C" void kernel_launch(void* const* d_in, const int* in_sizes, int n_in,
                              void* d_out, int out_size, void* d_ws, size_t ws_size,
                              hipStream_t stream)
{
    const float* x_old = (const float*)d_in[0];
    const float* x_cur = (const float*)d_in[1];
    const float* A     = (const float*)d_in[2];
    const float* b     = (const float*)d_in[3];
    const float* mu    = (const float*)d_in[4];
    const float* sm    = (const float*)d_in[5];
    const float* Wu1   = (const float*)d_in[6];
    const float* Wu2   = (const float*)d_in[7];
    const float* Wu3   = (const float*)d_in[8];
    const float* Wu4   = (const float*)d_in[9];
    const float* Ws1   = (const float*)d_in[10];
    const float* Ws2   = (const float*)d_in[11];
    const float* Ws3   = (const float*)d_in[12];
    const float* Ws4   = (const float*)d_in[13];
    float* out = (float*)d_out;

    float* ws      = (float*)d_ws;
    float* ws_gp   = ws;                           // 256 * DIM
    float* ws_sc   = ws_gp  + (size_t)256 * DIM;   // 512
    float* ws_red  = ws_sc  + 512;                 // 640
    float* ws_grad = ws_red + 640;                 // DIM

    k1_fused  <<<256, 1024, 0, stream>>>(A, x_cur, x_old, b, ws_gp, ws_sc);
    k2_fused  <<<64,  1024, 0, stream>>>(ws_gp, x_cur, x_old, mu, sm, ws_grad, ws_red);
    k34_update<<<64,  256,  0, stream>>>(ws_sc, ws_red, ws_grad, x_cur, x_old, mu, sm,
                                         Ws1, Ws2, Ws3, Ws4, Wu1, Wu2, Wu3, Wu4, out);
}

// Round 8
// 118.186 us; speedup vs baseline: 2.7978x; 1.3436x over previous
//
#include <hip/hip_runtime.h>
#include <math.h>

#define DIM   16384
#define NOBS  8192
#define EPSN  1e-20f

__device__ __forceinline__ float softf(float v, float tau) {
    float a = fmaxf(fabsf(v) - tau, 0.0f);
    return copysignf(a, v);   // v==0 -> +0, matches sign(0)*x == 0
}

__device__ __forceinline__ float dot4(float4 a, float4 b) {
    return a.x * b.x + a.y * b.y + a.z * b.z + a.w * b.w;
}

__device__ __forceinline__ float sum16(const float* p) {
    const float4* q = (const float4*)p;
    float4 s0 = q[0], s1 = q[1], s2 = q[2], s3 = q[3];
    float a = (s0.x + s0.y) + (s0.z + s0.w);
    float b = (s1.x + s1.y) + (s1.z + s1.w);
    float c = (s2.x + s2.y) + (s2.z + s2.w);
    float d = (s3.x + s3.y) + (s3.z + s3.w);
    return (a + b) + (c + d);
}

// Full-wave (64-lane) f32 sum on the VALU pipe via DPP (rocPRIM sequence).
// Result lands in lane 63. Replaces 6 ds_bpermute-based __shfl_down steps —
// keeps the reduction OFF the LDS pipe (16 waves/CU serialize there).
#define DPP_ADD(x, CTRL, RM, BM)                                               \
    ((x) + __builtin_bit_cast(float, __builtin_amdgcn_update_dpp(             \
               0, __builtin_bit_cast(int, (x)), (CTRL), (RM), (BM), false)))

__device__ __forceinline__ float wave_sum64(float x) {
    x = DPP_ADD(x, 0x111, 0xF, 0xF);   // row_shr:1
    x = DPP_ADD(x, 0x112, 0xF, 0xF);   // row_shr:2
    x = DPP_ADD(x, 0x114, 0xF, 0xF);   // row_shr:4
    x = DPP_ADD(x, 0x118, 0xF, 0xF);   // row_shr:8  -> lane15 of each row = row sum
    x = DPP_ADD(x, 0x142, 0xA, 0xF);   // row_bcast15 -> lanes 31,63 accumulate
    x = DPP_ADD(x, 0x143, 0xC, 0xF);   // row_bcast31 -> lane 63 = wave total
    return x;
}

// ---------------------------------------------------------------------------
// K1: fused  r = A@x_cur - b,  r_old = A@x_old - b,  grad_partial = A^T r
// 256 blocks x 1024 threads; block owns 32 rows; thread owns 16 columns.
// R2/R3-proven structure: xc/xo loop-invariant in registers, depth-1 prefetch
// (anxt -> acur copy), ONE __syncthreads per row, parity-double-buffered LDS
// dot partials, post-barrier sum16 broadcast. (R4-R7 detours: raw-barrier +
// macro restructure triggered allocator spills at VGPR=64; LDS-resident x
// put 8 ds_reads/row on the pre-barrier critical path. Both reverted.)
// Only change vs R3: DPP wave reduce (lane 63) instead of __shfl_down.
// ---------------------------------------------------------------------------
__global__ __launch_bounds__(1024) void k1_fused(
    const float* __restrict__ A, const float* __restrict__ xc,
    const float* __restrict__ xo, const float* __restrict__ b,
    float* __restrict__ ws_gp,   // [256][DIM] grad partials
    float* __restrict__ ws_sc)   // [256][2]   (sum r^2, sum r_old^2)
{
    const int t   = threadIdx.x;
    const int bid = blockIdx.x;
    __shared__ __align__(16) float redc[2][16];
    __shared__ __align__(16) float redo[2][16];
    __shared__ float bsh[32];

    const int row0 = bid * 32;
    if (t < 32) bsh[t] = b[row0 + t];

    const float4* xc4 = (const float4*)xc;
    const float4* xo4 = (const float4*)xo;

    float4 xcq[4], xoq[4], gpq[4];
#pragma unroll
    for (int k = 0; k < 4; ++k) {
        xcq[k] = xc4[k * 1024 + t];
        xoq[k] = xo4[k * 1024 + t];
        gpq[k] = make_float4(0.f, 0.f, 0.f, 0.f);
    }

    const float4* Abase = (const float4*)A + (size_t)row0 * (DIM / 4);
    float4 acur[4], anxt[4];
#pragma unroll
    for (int k = 0; k < 4; ++k) acur[k] = Abase[k * 1024 + t];

    float sum_r2 = 0.f, sum_ro2 = 0.f;
    __syncthreads();   // bsh visible

    for (int r = 0; r < 32; ++r) {
        // prefetch next row; completes during this row's compute + barrier
        if (r < 31) {
            const float4* An = Abase + (size_t)(r + 1) * (DIM / 4);
#pragma unroll
            for (int k = 0; k < 4; ++k) anxt[k] = An[k * 1024 + t];
        }

        float dc = 0.f, dn = 0.f;
#pragma unroll
        for (int k = 0; k < 4; ++k) {
            dc += dot4(acur[k], xcq[k]);
            dn += dot4(acur[k], xoq[k]);
        }
        dc = wave_sum64(dc);
        dn = wave_sum64(dn);
        if ((t & 63) == 63) {
            redc[r & 1][t >> 6] = dc;
            redo[r & 1][t >> 6] = dn;
        }
        __syncthreads();

        // every thread: rc via 4 broadcast float4 LDS reads + tree add
        float rc = sum16(redc[r & 1]) - bsh[r];
        if (t == 0) sum_r2 += rc * rc;
        if (t == 1) {
            float ro = sum16(redo[r & 1]) - bsh[r];
            sum_ro2 += ro * ro;
        }
#pragma unroll
        for (int k = 0; k < 4; ++k) {
            gpq[k].x += acur[k].x * rc;
            gpq[k].y += acur[k].y * rc;
            gpq[k].z += acur[k].z * rc;
            gpq[k].w += acur[k].w * rc;
        }
        if (r < 31) {
#pragma unroll
            for (int k = 0; k < 4; ++k) acur[k] = anxt[k];
        }
    }

    float4* gp4 = (float4*)(ws_gp + (size_t)bid * DIM);
#pragma unroll
    for (int k = 0; k < 4; ++k) gp4[k * 1024 + t] = gpq[k];
    if (t == 0) ws_sc[bid * 2 + 0] = sum_r2;
    if (t == 1) ws_sc[bid * 2 + 1] = sum_ro2;
}

// ---------------------------------------------------------------------------
// K2: fused partial-sum + finalize grad + all per-column stats.
// 256 blocks x 1024 threads (full CU coverage; R7 used 64 blocks -> 25% CUs).
// Block owns 64 columns; thread (s = t>>6, c = t&63) sums partials
// [16s, 16s+16) for column c; cross-slice combine in LDS; wave 0 computes the
// 10 stats for its 64 columns and reduces them in-wave.
// ---------------------------------------------------------------------------
__global__ __launch_bounds__(1024) void k2_fused(
    const float* __restrict__ ws_gp, const float* __restrict__ xc,
    const float* __restrict__ xo, const float* __restrict__ mu,
    const float* __restrict__ sm,
    float* __restrict__ grad, float* __restrict__ ws_red)  // [256][10]
{
    const int t = threadIdx.x;
    const int s = t >> 6;      // 16 slices
    const int c = t & 63;
    const int j0 = blockIdx.x * 64;

    __shared__ float sums[16][64];

    const float* base = ws_gp + (size_t)(s * 16) * DIM + j0 + c;
    float a0 = 0.f, a1 = 0.f, a2 = 0.f, a3 = 0.f;
#pragma unroll
    for (int i = 0; i < 4; ++i) {
        a0 += base[(size_t)(4 * i + 0) * DIM];
        a1 += base[(size_t)(4 * i + 1) * DIM];
        a2 += base[(size_t)(4 * i + 2) * DIM];
        a3 += base[(size_t)(4 * i + 3) * DIM];
    }
    sums[s][c] = (a0 + a1) + (a2 + a3);
    __syncthreads();

    if (t < 64) {
        const int jj = j0 + t;
        float g = 0.f;
#pragma unroll
        for (int ss = 0; ss < 16; ++ss) g += sums[ss][t];
        grad[jj] = g;

        const float x  = xc[jj];
        const float xv = xo[jj];
        const float z  = (x == 0.f) ? 1.f : 0.f;
        const float nz = 1.f - z;
        const float d  = x - xv;
        const float m = mu[0], L = sm[0];
        const float invL = 1.f / L;
        const float pv = softf(x - g * invL, m * invL);
        const float sv = x - pv;

        float vals[10];
        vals[0] = g * g * z;
        vals[1] = g * g * nz;
        vals[2] = d * d * z;
        vals[3] = d * d * nz;
        vals[4] = g * d * z;
        vals[5] = g * d * nz;
        vals[6] = fabsf(x);
        vals[7] = fabsf(xv);
        vals[8] = sv * sv * z;
        vals[9] = sv * sv * nz;

#pragma unroll
        for (int k = 0; k < 10; ++k) {
#pragma unroll
            for (int off = 32; off > 0; off >>= 1)
                vals[k] += __shfl_down(vals[k], off);
        }
        if (t == 0) {
#pragma unroll
            for (int k = 0; k < 10; ++k) ws_red[blockIdx.x * 10 + k] = vals[k];
        }
    }
}

// ---------------------------------------------------------------------------
// K34: fused scalar finish (redundant per block) + per-column update.
// 64 blocks x 256 threads. Phase A: batched reduce of 12 scalars + feats +
// step MLP -> alpha in LDS. Phase B: channels -> conv MLP -> soft-threshold.
// ---------------------------------------------------------------------------
__global__ __launch_bounds__(256) void k34_update(
    const float* __restrict__ ws_sc,   // [256][2]
    const float* __restrict__ ws_red,  // [256][10]
    const float* __restrict__ grad, const float* __restrict__ xc,
    const float* __restrict__ xo, const float* __restrict__ mu,
    const float* __restrict__ sm,
    const float* __restrict__ Ws1, const float* __restrict__ Ws2,
    const float* __restrict__ Ws3, const float* __restrict__ Ws4,
    const float* __restrict__ Wu1, const float* __restrict__ Wu2,
    const float* __restrict__ Wu3, const float* __restrict__ Wu4,
    float* __restrict__ out)
{
    __shared__ float w1[160], w2[400], w3[400], w4[40];
    __shared__ float sred[4][12];
    __shared__ float feats[12];
    __shared__ float ba[32], bb[32];
    __shared__ float alpha_sh[12];   // alpha[8], grad_norm, diff_norm, stop_norm

    const int t = threadIdx.x;
    for (int i = t; i < 160; i += 256) w1[i] = Wu1[i];
    for (int i = t; i < 400; i += 256) w2[i] = Wu2[i];
    for (int i = t; i < 400; i += 256) w3[i] = Wu3[i];
    if (t < 40) w4[t] = Wu4[t];

    // batched scalar reduction: 12 values, one barrier
    float v[12];
    v[0] = ws_sc[2 * t + 0];
    v[1] = ws_sc[2 * t + 1];
#pragma unroll
    for (int k = 0; k < 10; ++k) v[2 + k] = ws_red[t * 10 + k];
#pragma unroll
    for (int k = 0; k < 12; ++k) {
#pragma unroll
        for (int off = 32; off > 0; off >>= 1) v[k] += __shfl_down(v[k], off);
    }
    if ((t & 63) == 0) {
#pragma unroll
        for (int k = 0; k < 12; ++k) sred[t >> 6][k] = v[k];
    }
    __syncthreads();

    if (t == 0) {
        float r[12];
#pragma unroll
        for (int k = 0; k < 12; ++k)
            r[k] = (sred[0][k] + sred[1][k]) + (sred[2][k] + sred[3][k]);
        const float sum_r2 = r[0], sum_ro2 = r[1];
        const float gz2 = r[2], gnz2 = r[3], dz2 = r[4], dnz2 = r[5];
        const float gdz = r[6], gdnz = r[7], sxc = r[8], sxo = r[9];
        const float svz2 = r[10], svnz2 = r[11];

        const float grad_norm = sqrtf(gz2 + gnz2);
        const float diff_norm = sqrtf(dz2 + dnz2);
        const float stop_norm = sqrtf(svz2 + svnz2);
        const float m = mu[0];
        float smooth = 0.5f * sum_r2, old_smooth = 0.5f * sum_ro2;
        float nonsm = m * sxc, old_nonsm = m * sxo;
        float loss = smooth + nonsm, old_loss = old_smooth + old_nonsm;

        float fg = (grad_norm > EPSN) ? 1.f / grad_norm : 1.f;
        float fd = (diff_norm > EPSN) ? 1.f / diff_norm : 1.f;
        float fs = (stop_norm > EPSN) ? 1.f / stop_norm : 1.f;

        feats[0]  = m;
        feats[1]  = log1pf(old_loss) - log1pf(loss);
        feats[2]  = log1pf(old_smooth) - log1pf(smooth);
        feats[3]  = log1pf(old_nonsm) - log1pf(nonsm);
        feats[4]  = log1pf(grad_norm * fg * sqrtf(gz2));
        feats[5]  = log1pf(grad_norm * fg * sqrtf(gnz2));
        feats[6]  = log1pf(diff_norm * fd * sqrtf(dz2));
        feats[7]  = log1pf(diff_norm * fd * sqrtf(dnz2));
        feats[8]  = log1pf(stop_norm * fs * sqrtf(svz2));
        feats[9]  = log1pf(stop_norm * fs * sqrtf(svnz2));
        feats[10] = gdz  * fg * fd;
        feats[11] = gdnz * fg * fd;
        alpha_sh[8]  = grad_norm;
        alpha_sh[9]  = diff_norm;
        alpha_sh[10] = stop_norm;
    }
    __syncthreads();

    // step MLP: 12 -> 30 -> 20 -> 10 -> 8
    if (t < 30) {
        float s0 = 0.f;
#pragma unroll
        for (int k = 0; k < 12; ++k) s0 += Ws1[t * 12 + k] * feats[k];
        ba[t] = fmaxf(s0, 0.f);
    }
    __syncthreads();
    if (t < 20) {
        float s0 = 0.f;
#pragma unroll
        for (int k = 0; k < 30; ++k) s0 += Ws2[t * 30 + k] * ba[k];
        bb[t] = fmaxf(s0, 0.f);
    }
    __syncthreads();
    if (t < 10) {
        float s0 = 0.f;
#pragma unroll
        for (int k = 0; k < 20; ++k) s0 += Ws3[t * 20 + k] * bb[k];
        ba[t] = fmaxf(s0, 0.f);
    }
    __syncthreads();
    if (t < 8) {
        float s0 = 0.f;
#pragma unroll
        for (int k = 0; k < 10; ++k) s0 += Ws4[t * 10 + k] * ba[k];
        alpha_sh[t] = s0;
    }
    __syncthreads();

    // ---- phase B: per-column update ----
    const int j = blockIdx.x * 256 + t;
    const float m = mu[0], L = sm[0];
    const float invL = 1.f / L;
    const float gn = alpha_sh[8], dn = alpha_sh[9], sn = alpha_sh[10];
    float a[8];
#pragma unroll
    for (int k = 0; k < 8; ++k) a[k] = alpha_sh[k];

    const float g  = grad[j];
    const float x  = xc[j];
    const float xv = xo[j];
    const float z  = (x == 0.f) ? 1.f : 0.f;
    const float nz = 1.f - z;

    const float fg = (gn > EPSN) ? 1.f / gn : 1.f;
    const float fd = (dn > EPSN) ? 1.f / dn : 1.f;
    const float fs = (sn > EPSN) ? 1.f / sn : 1.f;
    const float gg = (gn > EPSN) ? g : gn * g;   // grad_norm * normalized_grad

    const float pv = softf(x - gg * invL, m * invL);
    const float sv = x - pv;

    const float gN = g * fg;
    const float dN = (x - xv) * fd;
    const float sN = sv * fs;

    float ch[8];
    ch[0] = a[0] * gN * z;
    ch[1] = a[1] * gN * nz;
    ch[2] = a[2] * sN * z;
    ch[3] = a[3] * sN * nz;
    ch[4] = a[4] * dN * z;
    ch[5] = a[5] * dN * nz;
    ch[6] = a[6] * (gN * nz) * (dN * nz);
    ch[7] = a[7] * (gN * z) * (dN * z);

    float h1[20];
#pragma unroll
    for (int i = 0; i < 20; ++i) {
        float s0 = 0.f;
#pragma unroll
        for (int k = 0; k < 8; ++k) s0 += w1[i * 8 + k] * ch[k];
        h1[i] = fmaxf(s0, 0.f);
    }
    float h2[20];
#pragma unroll
    for (int i = 0; i < 20; ++i) {
        float s0 = 0.f;
#pragma unroll
        for (int k = 0; k < 20; ++k) s0 += w2[i * 20 + k] * h1[k];
        h2[i] = fmaxf(s0, 0.f);
    }
    float h3[20];
#pragma unroll
    for (int i = 0; i < 20; ++i) {
        float s0 = 0.f;
#pragma unroll
        for (int k = 0; k < 20; ++k) s0 += w3[i * 20 + k] * h2[k];
        h3[i] = fmaxf(s0, 0.f);
    }
    float d0 = 0.f, d1 = 0.f;
#pragma unroll
    for (int k = 0; k < 20; ++k) {
        d0 += w4[k] * h3[k];
        d1 += w4[20 + k] * h3[k];
    }

    const float dir1 = d0 * z;
    const float dir2 = d1 * nz;
    const float arg  = x + (dir1 - gg + dn * dir2) * invL;
    out[j] = softf(arg, m * invL);
}

// ---------------------------------------------------------------------------
extern "C" void kernel_launch(void* const* d_in, const int* in_sizes, int n_in,
                              void* d_out, int out_size, void* d_ws, size_t ws_size,
                              hipStream_t stream)
{
    const float* x_old = (const float*)d_in[0];
    const float* x_cur = (const float*)d_in[1];
    const float* A     = (const float*)d_in[2];
    const float* b     = (const float*)d_in[3];
    const float* mu    = (const float*)d_in[4];
    const float* sm    = (const float*)d_in[5];
    const float* Wu1   = (const float*)d_in[6];
    const float* Wu2   = (const float*)d_in[7];
    const float* Wu3   = (const float*)d_in[8];
    const float* Wu4   = (const float*)d_in[9];
    const float* Ws1   = (const float*)d_in[10];
    const float* Ws2   = (const float*)d_in[11];
    const float* Ws3   = (const float*)d_in[12];
    const float* Ws4   = (const float*)d_in[13];
    float* out = (float*)d_out;

    float* ws      = (float*)d_ws;
    float* ws_gp   = ws;                           // 256 * DIM
    float* ws_sc   = ws_gp  + (size_t)256 * DIM;   // 512
    float* ws_red  = ws_sc  + 512;                 // 2560
    float* ws_grad = ws_red + 2560;                // DIM

    k1_fused  <<<256, 1024, 0, stream>>>(A, x_cur, x_old, b, ws_gp, ws_sc);
    k2_fused  <<<256, 1024, 0, stream>>>(ws_gp, x_cur, x_old, mu, sm, ws_grad, ws_red);
    k34_update<<<64,  256,  0, stream>>>(ws_sc, ws_red, ws_grad, x_cur, x_old, mu, sm,
                                         Ws1, Ws2, Ws3, Ws4, Wu1, Wu2, Wu3, Wu4, out);
}